// Round 10
// baseline (977.796 us; speedup 1.0000x reference)
//
#include <hip/hip_runtime.h>

// SimAttn: out = softmax(1000*softmax(QK^T/sqrt(dk))) @ V, fp32 I/O.
// v10 = v9 math (fragment-major pre-layout, direct global fragment loads, no
// per-chunk LDS/barriers) + K-split x4 inside a 256-thread block:
//   wave w handles chunks kc = 4t+w (16 chunks/pass). Cross-wave coupling:
//   one stats merge (LDS+barrier) after pass 1, and a 4-phase ybuf reduction
//   (16KB LDS) at the end. Grid 2048 blocks -> 8192 waves (~6/SIMD by VGPR)
//   vs v9's 2048 waves (2/SIMD): fills the MFMA/trans/VALU latency gaps.
// pass 1: f16 32x32x16 QK^T (swapped) -> row max m, l8 = sum 2^(s*SC2-MOFF2)
// pass 2: identical scores -> p = 2^..., w = 2^(fmaf(p,ul2,mcu2)) <= ~1,
//         w -> A-frag via one shfl_xor(32)+selects, PV 32x32x16;
//         y-reduce across waves, normalize by sum(w).

typedef __attribute__((ext_vector_type(4))) float f32x4;
typedef __attribute__((ext_vector_type(16))) float f32x16;
typedef __attribute__((ext_vector_type(8))) _Float16 h16x8;
typedef __attribute__((ext_vector_type(4))) _Float16 h16x4;
typedef __attribute__((ext_vector_type(8))) short s16x8;
typedef __attribute__((ext_vector_type(4))) short s16x4;
typedef __attribute__((ext_vector_type(2))) unsigned int u32x2;
typedef __attribute__((ext_vector_type(4))) unsigned int u32x4;

#define NB 4
#define T_ 2048
#define D_ 1024
#define NH 8
#define DK 128
#define NKC9 64                     // 32-key chunks
#define NWG9 2048                   // blocks: one 32-q tile each
#define SCALE 0.08838834764831845f  // 1/sqrt(128)
#define SC2   0.12751741689839996f  // SCALE * log2(e)
#define MOFF2 11.541560327111707f   // 8 * log2(e)
#define L2E   1.4426950408889634f

__device__ __forceinline__ unsigned int pk2(float a, float b) {
  return __builtin_bit_cast(unsigned int, __builtin_amdgcn_cvt_pkrtz(a, b));
}
#define H8(p) __builtin_bit_cast(h16x8, *(const s16x8*)(p))

// ---- pre-kernel: K,V fp32 -> fragment-major f16 panels in d_ws -------------
__global__ __launch_bounds__(256) void prep9(const float* __restrict__ Kg,
                                             const float* __restrict__ Vg,
                                             unsigned short* __restrict__ Kf,
                                             unsigned short* __restrict__ Vf) {
  __shared__ unsigned short klds[32][136];
  __shared__ unsigned short vlds[32][136];
  const int t   = threadIdx.x;
  const int bid = blockIdx.x;
  const int bh = bid >> 6, kc = bid & 63;
  const int b = bh >> 3, h = bh & 7;
  const float* ks = Kg + ((size_t)b * T_ + kc * 32) * D_ + h * DK;
  const float* vs = Vg + ((size_t)b * T_ + kc * 32) * D_ + h * DK;
#pragma unroll
  for (int i = 0; i < 4; ++i) {
    const int gidx = i * 256 + t;
    const int row = gidx >> 5, c4 = gidx & 31;
    f32x4 kv = *(const f32x4*)(ks + (size_t)row * D_ + c4 * 4);
    f32x4 vv = *(const f32x4*)(vs + (size_t)row * D_ + c4 * 4);
    h16x4 kh, vh;
#pragma unroll
    for (int j = 0; j < 4; ++j) { kh[j] = (_Float16)kv[j]; vh[j] = (_Float16)vv[j]; }
    *(s16x4*)&klds[row][c4 * 4] = __builtin_bit_cast(s16x4, kh);
    *(s16x4*)&vlds[row][c4 * 4] = __builtin_bit_cast(s16x4, vh);
  }
  __syncthreads();
  unsigned short* kd = Kf + ((size_t)bh * 64 + kc) * 4096;
  unsigned short* vd = Vf + ((size_t)bh * 64 + kc) * 4096;
#pragma unroll
  for (int i = 0; i < 2; ++i) {
    const int gr = i * 256 + t;          // granule 0..511 (16B each)
    const int sl = gr >> 6, l = gr & 63; // sl: step (K) / hh*4+dt (V)
    const int gg = l >> 5, cc = l & 31;
    *(s16x8*)(kd + gr * 8) = *(const s16x8*)&klds[cc][sl * 16 + gg * 8];
    const int hh = sl >> 2, dt = sl & 3;
    s16x8 tv;
#pragma unroll
    for (int j = 0; j < 8; ++j)
      tv[j] = (short)vlds[hh * 16 + gg * 8 + j][dt * 32 + cc];
    *(s16x8*)(vd + gr * 8) = tv;
  }
}

// ---- main kernel: 256 thr = 4 waves, K-split x4, one 32-q tile per block ---
__global__ __launch_bounds__(256, 6) void simattn_v10(
    const float* __restrict__ Qg, const unsigned short* __restrict__ Kf,
    const unsigned short* __restrict__ Vf, float* __restrict__ Og) {
  __shared__ float ybuf[32 * 128];     // 16 KB
  __shared__ float stats[4][2][32];    // per-wave (m, l8) per q
  __shared__ float wsum[4][32];        // per-wave Wl per q

  const int tid  = threadIdx.x;
  const int w    = tid >> 6;       // wave 0..3 (k-split)
  const int lane = tid & 63;
  const int c = lane & 31, g = lane >> 5;
  const bool hi = (g != 0);

  // XCD-chunked swizzle (2048 % 8 == 0 -> bijective)
  const int bid = blockIdx.x;
  const int blk = (bid & 7) * (NWG9 >> 3) + (bid >> 3);
  const int qt = blk & 63, h = (blk >> 6) & 7, b = blk >> 9;
  const int q0 = qt * 32;
  const size_t bhf = (size_t)b * (T_ * D_) + (size_t)h * DK;
  const int bhp = b * NH + h;
  const unsigned short* kb0 = Kf + (size_t)bhp * (64 * 4096) + lane * 8;
  const unsigned short* vb0 = Vf + (size_t)bhp * (64 * 4096) + lane * 8;

  // Q B-frags: lane holds Q[q = q0+c][d = step*16 + g*8 + i] (same in all waves)
  h16x8 qf[8];
  {
    const float* qp = Qg + bhf + (size_t)(q0 + c) * D_;
#pragma unroll
    for (int step = 0; step < 8; ++step) {
      const int d0 = step * 16 + g * 8;
      f32x4 x0 = *(const f32x4*)(qp + d0);
      f32x4 x1 = *(const f32x4*)(qp + d0 + 4);
#pragma unroll
      for (int i = 0; i < 4; ++i) {
        qf[step][i]     = (_Float16)x0[i];
        qf[step][i + 4] = (_Float16)x1[i];
      }
    }
  }

  // ---- pass 1 over this wave's chunks: kc = 4t + w -------------------------
  float msc = -3.0e38f, l8 = 0.f;
#pragma unroll 2
  for (int t = 0; t < 16; ++t) {
    const unsigned short* kp = kb0 + (4 * t + w) * 4096;
    s16x8 kb[8];
#pragma unroll
    for (int s = 0; s < 8; ++s) kb[s] = *(const s16x8*)(kp + s * 512);
    f32x16 st;
#pragma unroll
    for (int i = 0; i < 16; ++i) st[i] = 0.f;
#pragma unroll
    for (int s = 0; s < 8; ++s)
      st = __builtin_amdgcn_mfma_f32_32x32x16_f16(__builtin_bit_cast(h16x8, kb[s]),
                                                  qf[s], st, 0, 0, 0);
    float e[16];
#pragma unroll
    for (int r = 0; r < 16; ++r) {
      msc = fmaxf(msc, st[r]);
      e[r] = __builtin_amdgcn_exp2f(fmaf(st[r], SC2, -MOFF2));
    }
    float s0 = 0.f, s1 = 0.f, s2 = 0.f, s3 = 0.f;
#pragma unroll
    for (int r = 0; r < 4; ++r) {
      s0 += e[r]; s1 += e[4 + r]; s2 += e[8 + r]; s3 += e[12 + r];
    }
    l8 += (s0 + s1) + (s2 + s3);
  }
  msc = fmaxf(msc, __shfl_xor(msc, 32));
  l8 += __shfl_xor(l8, 32);
  if (lane < 32) { stats[w][0][c] = msc; stats[w][1][c] = l8; }
  __syncthreads();
  {
    const float m01 = fmaxf(stats[0][0][c], stats[1][0][c]);
    const float m23 = fmaxf(stats[2][0][c], stats[3][0][c]);
    msc = fmaxf(m01, m23);
    l8 = (stats[0][1][c] + stats[1][1][c]) + (stats[2][1][c] + stats[3][1][c]);
  }
  const float pm   = __builtin_amdgcn_exp2f(fmaf(msc, SC2, -MOFF2)); // = max p
  const float ul2  = (1000.0f / l8) * L2E;
  const float mcu2 = -ul2 * pm;

  // ---- pass 2 over this wave's chunks: scores -> w -> PV (partial y) -------
  f32x16 y[4];
#pragma unroll
  for (int dt = 0; dt < 4; ++dt)
#pragma unroll
    for (int i = 0; i < 16; ++i) y[dt][i] = 0.f;
  float Wl = 0.f;

  for (int t = 0; t < 16; ++t) {
    const unsigned short* kp = kb0 + (4 * t + w) * 4096;
    const unsigned short* vp = vb0 + (4 * t + w) * 4096;
    s16x8 kb[8], vb[8];
#pragma unroll
    for (int s = 0; s < 8; ++s) kb[s] = *(const s16x8*)(kp + s * 512);
#pragma unroll
    for (int s = 0; s < 8; ++s) vb[s] = *(const s16x8*)(vp + s * 512);
    f32x16 st;
#pragma unroll
    for (int i = 0; i < 16; ++i) st[i] = 0.f;
#pragma unroll
    for (int s = 0; s < 8; ++s)
      st = __builtin_amdgcn_mfma_f32_32x32x16_f16(__builtin_bit_cast(h16x8, kb[s]),
                                                  qf[s], st, 0, 0, 0);

    unsigned pw[8];
#pragma unroll
    for (int m = 0; m < 8; ++m) {
      const float p0 = __builtin_amdgcn_exp2f(fmaf(st[2 * m], SC2, -MOFF2));
      const float p1 = __builtin_amdgcn_exp2f(fmaf(st[2 * m + 1], SC2, -MOFF2));
      const float w0 = __builtin_amdgcn_exp2f(fmaf(p0, ul2, mcu2));
      const float w1 = __builtin_amdgcn_exp2f(fmaf(p1, ul2, mcu2));
      Wl += w0 + w1;
      pw[m] = pk2(w0, w1);
    }

#pragma unroll
    for (int hh = 0; hh < 2; ++hh) {
      const unsigned t0 = hi ? pw[4 * hh] : pw[4 * hh + 2];
      const unsigned t1 = hi ? pw[4 * hh + 1] : pw[4 * hh + 3];
      const unsigned r0 = (unsigned)__shfl_xor((int)t0, 32);
      const unsigned r1 = (unsigned)__shfl_xor((int)t1, 32);
      u32x4 aw;
      aw[0] = hi ? r0 : pw[4 * hh];
      aw[1] = hi ? r1 : pw[4 * hh + 1];
      aw[2] = hi ? pw[4 * hh + 2] : r0;
      aw[3] = hi ? pw[4 * hh + 3] : r1;
      const h16x8 af = __builtin_bit_cast(h16x8, aw);
#pragma unroll
      for (int dt = 0; dt < 4; ++dt) {
        y[dt] = __builtin_amdgcn_mfma_f32_32x32x16_f16(
            af, __builtin_bit_cast(h16x8, vb[hh * 4 + dt]), y[dt], 0, 0, 0);
      }
    }
  }

  // ---- cross-wave reduction ------------------------------------------------
  Wl += __shfl_xor(Wl, 32);
  if (lane < 32) wsum[w][c] = Wl;

  // y: sequential accumulate into ybuf (wave-exclusive phases)
  if (w == 0) {
#pragma unroll
    for (int r = 0; r < 16; ++r) {
      const int qrow = (r & 3) + 8 * (r >> 2) + 4 * g;
#pragma unroll
      for (int dt = 0; dt < 4; ++dt) ybuf[qrow * 128 + dt * 32 + c] = y[dt][r];
    }
  }
  __syncthreads();
#pragma unroll
  for (int ww = 1; ww < 4; ++ww) {
    if (w == ww) {
#pragma unroll
      for (int r = 0; r < 16; ++r) {
        const int qrow = (r & 3) + 8 * (r >> 2) + 4 * g;
#pragma unroll
        for (int dt = 0; dt < 4; ++dt) ybuf[qrow * 128 + dt * 32 + c] += y[dt][r];
      }
    }
    __syncthreads();
  }

  // ---- normalize and store: wave w covers q-rows [w*8, w*8+8) --------------
  const int row = w * 8 + (lane >> 3);
  const int d0 = (lane & 7) * 16;
  const float Wt = (wsum[0][row] + wsum[1][row]) + (wsum[2][row] + wsum[3][row]);
  const float winv = 1.0f / Wt;
  float* ob = Og + bhf + (size_t)(q0 + row) * D_ + d0;
#pragma unroll
  for (int i = 0; i < 4; ++i) {
    f32x4 v = *(const f32x4*)&ybuf[row * 128 + d0 + i * 4];
    v[0] *= winv; v[1] *= winv; v[2] *= winv; v[3] *= winv;
    *(f32x4*)(ob + i * 4) = v;
  }
}

// ---- fallback: R3-style kernel (used when ws_size is too small) ------------
__global__ __launch_bounds__(256, 4) void simattn_fb(
    const float* __restrict__ Qg, const float* __restrict__ Kg,
    const float* __restrict__ Vg, float* __restrict__ Og) {
  __shared__ __align__(16) unsigned short kfb[64][DK];
  __shared__ __align__(16) unsigned short vtb[DK][64];
  __shared__ __align__(16) unsigned int   wlb[4][16][32];

  const int tid  = threadIdx.x;
  const int wid  = tid >> 6;
  const int lane = tid & 63;
  const int lr   = lane & 15;
  const int lg   = lane >> 4;

  const int blk  = blockIdx.x;
  const int qblk = blk & 31;
  const int h    = (blk >> 5) & (NH - 1);
  const int b    = blk >> 8;
  const int q0   = qblk * 64;
  const size_t bh = (size_t)b * (T_ * D_) + (size_t)h * DK;

  h16x8 qf[4];
  {
    const float* qp = Qg + bh + (size_t)(q0 + wid * 16 + lr) * D_;
#pragma unroll
    for (int s = 0; s < 4; ++s) {
      const int d0 = s * 32 + lg * 8;
      f32x4 x0 = *(const f32x4*)(qp + d0);
      f32x4 x1 = *(const f32x4*)(qp + d0 + 4);
#pragma unroll
      for (int i = 0; i < 4; ++i) { qf[s][i] = (_Float16)x0[i]; qf[s][i+4] = (_Float16)x1[i]; }
    }
  }
  auto stageK = [&](int kc) {
    const float* kp = Kg + bh + (size_t)kc * 64 * D_;
#pragma unroll
    for (int p = 0; p < 8; ++p) {
      const int j = tid + p * 256;
      const int row = j >> 5, c4 = j & 31;
      f32x4 v = *(const f32x4*)(kp + (size_t)row * D_ + c4 * 4);
      h16x4 hv;
#pragma unroll
      for (int i = 0; i < 4; ++i) hv[i] = (_Float16)v[i];
      const int e = (c4 * 4) ^ ((row & 7) << 3);
      *(s16x4*)&kfb[row][e] = __builtin_bit_cast(s16x4, hv);
    }
  };
  auto qkT = [&](f32x4* st) {
#pragma unroll
    for (int nt = 0; nt < 4; ++nt) st[nt] = (f32x4){0.f, 0.f, 0.f, 0.f};
#pragma unroll
    for (int s = 0; s < 4; ++s) {
#pragma unroll
      for (int nt = 0; nt < 4; ++nt) {
        const int kr = nt * 16 + lr;
        const int e = (s * 32 + lg * 8) ^ ((kr & 7) << 3);
        st[nt] = __builtin_amdgcn_mfma_f32_16x16x32_f16(H8(&kfb[kr][e]), qf[s], st[nt], 0, 0, 0);
      }
    }
  };
  float msc = -3.0e38f, l8 = 0.f;
  for (int kc = 0; kc < 32; ++kc) {
    __syncthreads();
    stageK(kc);
    __syncthreads();
    f32x4 st[4];
    qkT(st);
#pragma unroll
    for (int nt = 0; nt < 4; ++nt)
#pragma unroll
      for (int r = 0; r < 4; ++r) {
        const float s = st[nt][r];
        msc = fmaxf(msc, s);
        l8 += __builtin_amdgcn_exp2f(fmaf(s, SC2, -MOFF2));
      }
  }
  msc = fmaxf(msc, __shfl_xor(msc, 16));
  msc = fmaxf(msc, __shfl_xor(msc, 32));
  l8 += __shfl_xor(l8, 16);
  l8 += __shfl_xor(l8, 32);
  const float pm   = __builtin_amdgcn_exp2f(fmaf(msc, SC2, -MOFF2));
  const float ul2  = (1000.0f / l8) * L2E;
  const float mcu2 = -ul2 * pm;

  f32x4 y[8];
#pragma unroll
  for (int dt = 0; dt < 8; ++dt) y[dt] = (f32x4){0.f, 0.f, 0.f, 0.f};
  float Wl = 0.f;
  const int dv  = tid & 127;
  const int kg0 = tid >> 7;
  for (int kc = 0; kc < 32; ++kc) {
    __syncthreads();
    stageK(kc);
    {
      const float* vp = Vg + bh + (size_t)kc * 64 * D_ + dv;
#pragma unroll
      for (int i = 0; i < 4; ++i) {
        const int kg = kg0 + 2 * i;
        const float* vq = vp + (size_t)kg * 8 * D_;
        u32x4 pv;
        pv[0] = pk2(vq[0], vq[D_]);
        pv[1] = pk2(vq[2 * D_], vq[3 * D_]);
        pv[2] = pk2(vq[4 * D_], vq[5 * D_]);
        pv[3] = pk2(vq[6 * D_], vq[7 * D_]);
        *(u32x4*)&vtb[dv][(kg ^ (dv & 7)) * 8] = pv;
      }
    }
    __syncthreads();
    f32x4 st[4];
    qkT(st);
#pragma unroll
    for (int nt = 0; nt < 4; ++nt) {
      float w[4];
#pragma unroll
      for (int r = 0; r < 4; ++r) {
        const float pp = __builtin_amdgcn_exp2f(fmaf(st[nt][r], SC2, -MOFF2));
        w[r] = __builtin_amdgcn_exp2f(fmaf(pp, ul2, mcu2));
      }
      Wl += (w[0] + w[1]) + (w[2] + w[3]);
      u32x2 pk;
      pk[0] = pk2(w[0], w[1]);
      pk[1] = pk2(w[2], w[3]);
      *(u32x2*)&wlb[wid][lr][(nt * 8 + lg * 2) ^ ((lr & 7) << 2)] = pk;
    }
#pragma unroll
    for (int ks = 0; ks < 2; ++ks) {
      h16x8 af = H8((const unsigned short*)&wlb[wid][lr][(ks * 16 + lg * 4) ^ ((lr & 7) << 2)]);
#pragma unroll
      for (int dt = 0; dt < 8; ++dt) {
        const int d = dt * 16 + lr;
        h16x8 vf = H8(&vtb[d][((ks * 4 + lg) ^ (d & 7)) * 8]);
        y[dt] = __builtin_amdgcn_mfma_f32_16x16x32_f16(af, vf, y[dt], 0, 0, 0);
      }
    }
  }
  Wl += __shfl_xor(Wl, 16);
  Wl += __shfl_xor(Wl, 32);
  const float winv = 1.0f / Wl;
  float* op = Og + bh + (size_t)(q0 + wid * 16) * D_;
#pragma unroll
  for (int r = 0; r < 4; ++r) {
    const float wv = __shfl(winv, lg * 4 + r);
#pragma unroll
    for (int dt = 0; dt < 8; ++dt)
      op[(size_t)(lg * 4 + r) * D_ + dt * 16 + lr] = y[dt][r] * wv;
  }
}

extern "C" void kernel_launch(void* const* d_in, const int* in_sizes, int n_in,
                              void* d_out, int out_size, void* d_ws, size_t ws_size,
                              hipStream_t stream) {
  (void)in_sizes; (void)n_in; (void)out_size;
  const float* Q = (const float*)d_in[0];
  const float* K = (const float*)d_in[1];
  const float* V = (const float*)d_in[2];
  float* O = (float*)d_out;
  const size_t half = (size_t)NB * NH * T_ * DK * 2;  // 16.78 MB per tensor
  if (ws_size >= 2 * half) {
    unsigned short* Kf = (unsigned short*)d_ws;
    unsigned short* Vf = (unsigned short*)((char*)d_ws + half);
    prep9<<<dim3(2048), 256, 0, stream>>>(K, V, Kf, Vf);
    simattn_v10<<<dim3(NWG9), 256, 0, stream>>>(Q, Kf, Vf, O);
  } else {
    simattn_fb<<<dim3(NB * NH * (T_ / 64)), 256, 0, stream>>>(Q, K, V, O);
  }
}

// Round 11
// 171.605 us; speedup vs baseline: 5.6980x; 5.6980x over previous
//
#include <hip/hip_runtime.h>

// SimAttn: out = softmax(1000*softmax(QK^T/sqrt(dk))) @ V, fp32 I/O.
// v11 = v10 (fragment-major pre-layout, K-split x4 in a 256-thread block,
// one stats merge + end-of-kernel y reduction) with the register budget FIXED:
//   __launch_bounds__(256,3) -> 512/3 = 170 combined VGPR+AGPR per wave
//   (v10's (256,6) forced an ~85-reg budget and spilled y/st to scratch:
//    VGPR_Count=40, WRITE_SIZE=2.7GB, 977us).
// kb/vb fragments are loaded per-use (live 4-8 regs, not 32+32) so the
// allocator fits qf(32V) + y(64A) + st(16A) + misc in budget.
// Math (validated R8-R10): pass1 f16 32x32x16 swapped QK^T -> m, l8=sum 2^x;
// pass2 identical scores -> w = 2^(fmaf(p,ul2,mcu2)) <= ~1, w -> A-frag via
// one shfl_xor(32)+selects, PV 32x32x16; y-reduce across waves; /sum(w).

typedef __attribute__((ext_vector_type(4))) float f32x4;
typedef __attribute__((ext_vector_type(16))) float f32x16;
typedef __attribute__((ext_vector_type(8))) _Float16 h16x8;
typedef __attribute__((ext_vector_type(4))) _Float16 h16x4;
typedef __attribute__((ext_vector_type(8))) short s16x8;
typedef __attribute__((ext_vector_type(4))) short s16x4;
typedef __attribute__((ext_vector_type(2))) unsigned int u32x2;
typedef __attribute__((ext_vector_type(4))) unsigned int u32x4;

#define NB 4
#define T_ 2048
#define D_ 1024
#define NH 8
#define DK 128
#define NWG9 2048                   // blocks: one 32-q tile each
#define SCALE 0.08838834764831845f  // 1/sqrt(128)
#define SC2   0.12751741689839996f  // SCALE * log2(e)
#define MOFF2 11.541560327111707f   // 8 * log2(e)
#define L2E   1.4426950408889634f

__device__ __forceinline__ unsigned int pk2(float a, float b) {
  return __builtin_bit_cast(unsigned int, __builtin_amdgcn_cvt_pkrtz(a, b));
}
#define H8(p) __builtin_bit_cast(h16x8, *(const s16x8*)(p))

// ---- pre-kernel: K,V fp32 -> fragment-major f16 panels in d_ws -------------
__global__ __launch_bounds__(256) void prep9(const float* __restrict__ Kg,
                                             const float* __restrict__ Vg,
                                             unsigned short* __restrict__ Kf,
                                             unsigned short* __restrict__ Vf) {
  __shared__ unsigned short klds[32][136];
  __shared__ unsigned short vlds[32][136];
  const int t   = threadIdx.x;
  const int bid = blockIdx.x;
  const int bh = bid >> 6, kc = bid & 63;
  const int b = bh >> 3, h = bh & 7;
  const float* ks = Kg + ((size_t)b * T_ + kc * 32) * D_ + h * DK;
  const float* vs = Vg + ((size_t)b * T_ + kc * 32) * D_ + h * DK;
#pragma unroll
  for (int i = 0; i < 4; ++i) {
    const int gidx = i * 256 + t;
    const int row = gidx >> 5, c4 = gidx & 31;
    f32x4 kv = *(const f32x4*)(ks + (size_t)row * D_ + c4 * 4);
    f32x4 vv = *(const f32x4*)(vs + (size_t)row * D_ + c4 * 4);
    h16x4 kh, vh;
#pragma unroll
    for (int j = 0; j < 4; ++j) { kh[j] = (_Float16)kv[j]; vh[j] = (_Float16)vv[j]; }
    *(s16x4*)&klds[row][c4 * 4] = __builtin_bit_cast(s16x4, kh);
    *(s16x4*)&vlds[row][c4 * 4] = __builtin_bit_cast(s16x4, vh);
  }
  __syncthreads();
  unsigned short* kd = Kf + ((size_t)bh * 64 + kc) * 4096;
  unsigned short* vd = Vf + ((size_t)bh * 64 + kc) * 4096;
#pragma unroll
  for (int i = 0; i < 2; ++i) {
    const int gr = i * 256 + t;          // granule 0..511 (16B each)
    const int sl = gr >> 6, l = gr & 63; // sl: step (K) / hh*4+dt (V)
    const int gg = l >> 5, cc = l & 31;
    *(s16x8*)(kd + gr * 8) = *(const s16x8*)&klds[cc][sl * 16 + gg * 8];
    const int hh = sl >> 2, dt = sl & 3;
    s16x8 tv;
#pragma unroll
    for (int j = 0; j < 8; ++j)
      tv[j] = (short)vlds[hh * 16 + gg * 8 + j][dt * 32 + cc];
    *(s16x8*)(vd + gr * 8) = tv;
  }
}

// ---- main kernel: 256 thr = 4 waves, K-split x4, one 32-q tile per block ---
__global__ __launch_bounds__(256, 3) void simattn_v11(
    const float* __restrict__ Qg, const unsigned short* __restrict__ Kf,
    const unsigned short* __restrict__ Vf, float* __restrict__ Og) {
  __shared__ float ybuf[32 * 128];     // 16 KB
  __shared__ float stats[4][2][32];    // per-wave (m, l8) per q
  __shared__ float wsum[4][32];        // per-wave Wl per q

  const int tid  = threadIdx.x;
  const int w    = tid >> 6;       // wave 0..3 (k-split)
  const int lane = tid & 63;
  const int c = lane & 31, g = lane >> 5;
  const bool hi = (g != 0);

  // XCD-chunked swizzle (2048 % 8 == 0 -> bijective)
  const int bid = blockIdx.x;
  const int blk = (bid & 7) * (NWG9 >> 3) + (bid >> 3);
  const int qt = blk & 63, h = (blk >> 6) & 7, b = blk >> 9;
  const int q0 = qt * 32;
  const size_t bhf = (size_t)b * (T_ * D_) + (size_t)h * DK;
  const int bhp = b * NH + h;
  const unsigned short* kb0 = Kf + (size_t)bhp * (64 * 4096) + lane * 8;
  const unsigned short* vb0 = Vf + (size_t)bhp * (64 * 4096) + lane * 8;

  // Q B-frags: lane holds Q[q = q0+c][d = step*16 + g*8 + i] (same in all waves)
  h16x8 qf[8];
  {
    const float* qp = Qg + bhf + (size_t)(q0 + c) * D_;
#pragma unroll
    for (int step = 0; step < 8; ++step) {
      const int d0 = step * 16 + g * 8;
      f32x4 x0 = *(const f32x4*)(qp + d0);
      f32x4 x1 = *(const f32x4*)(qp + d0 + 4);
#pragma unroll
      for (int i = 0; i < 4; ++i) {
        qf[step][i]     = (_Float16)x0[i];
        qf[step][i + 4] = (_Float16)x1[i];
      }
    }
  }

  // ---- pass 1 over this wave's chunks: kc = 4t + w -------------------------
  float msc = -3.0e38f, l8 = 0.f;
  for (int t = 0; t < 16; ++t) {
    const unsigned short* kp = kb0 + (4 * t + w) * 4096;
    f32x16 st;
#pragma unroll
    for (int i = 0; i < 16; ++i) st[i] = 0.f;
#pragma unroll
    for (int s = 0; s < 8; ++s) {
      const s16x8 kb = *(const s16x8*)(kp + s * 512);  // per-step load (low live range)
      st = __builtin_amdgcn_mfma_f32_32x32x16_f16(__builtin_bit_cast(h16x8, kb),
                                                  qf[s], st, 0, 0, 0);
    }
    float e[16];
#pragma unroll
    for (int r = 0; r < 16; ++r) {
      msc = fmaxf(msc, st[r]);
      e[r] = __builtin_amdgcn_exp2f(fmaf(st[r], SC2, -MOFF2));
    }
    float s0 = 0.f, s1 = 0.f, s2 = 0.f, s3 = 0.f;
#pragma unroll
    for (int r = 0; r < 4; ++r) {
      s0 += e[r]; s1 += e[4 + r]; s2 += e[8 + r]; s3 += e[12 + r];
    }
    l8 += (s0 + s1) + (s2 + s3);
  }
  msc = fmaxf(msc, __shfl_xor(msc, 32));
  l8 += __shfl_xor(l8, 32);
  if (lane < 32) { stats[w][0][c] = msc; stats[w][1][c] = l8; }
  __syncthreads();
  {
    const float m01 = fmaxf(stats[0][0][c], stats[1][0][c]);
    const float m23 = fmaxf(stats[2][0][c], stats[3][0][c]);
    msc = fmaxf(m01, m23);
    l8 = (stats[0][1][c] + stats[1][1][c]) + (stats[2][1][c] + stats[3][1][c]);
  }
  const float pm   = __builtin_amdgcn_exp2f(fmaf(msc, SC2, -MOFF2)); // = max p
  const float ul2  = (1000.0f / l8) * L2E;
  const float mcu2 = -ul2 * pm;

  // ---- pass 2 over this wave's chunks: scores -> w -> PV (partial y) -------
  f32x16 y[4];
#pragma unroll
  for (int dt = 0; dt < 4; ++dt)
#pragma unroll
    for (int i = 0; i < 16; ++i) y[dt][i] = 0.f;
  float Wl = 0.f;

  for (int t = 0; t < 16; ++t) {
    const unsigned short* kp = kb0 + (4 * t + w) * 4096;
    const unsigned short* vp = vb0 + (4 * t + w) * 4096;
    f32x16 st;
#pragma unroll
    for (int i = 0; i < 16; ++i) st[i] = 0.f;
#pragma unroll
    for (int s = 0; s < 8; ++s) {
      const s16x8 kb = *(const s16x8*)(kp + s * 512);
      st = __builtin_amdgcn_mfma_f32_32x32x16_f16(__builtin_bit_cast(h16x8, kb),
                                                  qf[s], st, 0, 0, 0);
    }

    unsigned pw[8];
#pragma unroll
    for (int m = 0; m < 8; ++m) {
      const float p0 = __builtin_amdgcn_exp2f(fmaf(st[2 * m], SC2, -MOFF2));
      const float p1 = __builtin_amdgcn_exp2f(fmaf(st[2 * m + 1], SC2, -MOFF2));
      const float w0 = __builtin_amdgcn_exp2f(fmaf(p0, ul2, mcu2));
      const float w1 = __builtin_amdgcn_exp2f(fmaf(p1, ul2, mcu2));
      Wl += w0 + w1;
      pw[m] = pk2(w0, w1);
    }

#pragma unroll
    for (int hh = 0; hh < 2; ++hh) {
      const unsigned t0 = hi ? pw[4 * hh] : pw[4 * hh + 2];
      const unsigned t1 = hi ? pw[4 * hh + 1] : pw[4 * hh + 3];
      const unsigned r0 = (unsigned)__shfl_xor((int)t0, 32);
      const unsigned r1 = (unsigned)__shfl_xor((int)t1, 32);
      u32x4 aw;
      aw[0] = hi ? r0 : pw[4 * hh];
      aw[1] = hi ? r1 : pw[4 * hh + 1];
      aw[2] = hi ? pw[4 * hh + 2] : r0;
      aw[3] = hi ? pw[4 * hh + 3] : r1;
      const h16x8 af = __builtin_bit_cast(h16x8, aw);
#pragma unroll
      for (int dt = 0; dt < 4; ++dt) {
        const s16x8 vb = *(const s16x8*)(vp + (hh * 4 + dt) * 512);  // per-use load
        y[dt] = __builtin_amdgcn_mfma_f32_32x32x16_f16(
            af, __builtin_bit_cast(h16x8, vb), y[dt], 0, 0, 0);
      }
    }
  }

  // ---- cross-wave reduction ------------------------------------------------
  Wl += __shfl_xor(Wl, 32);
  if (lane < 32) wsum[w][c] = Wl;

  // y: sequential accumulate into ybuf (wave-exclusive phases)
  if (w == 0) {
#pragma unroll
    for (int r = 0; r < 16; ++r) {
      const int qrow = (r & 3) + 8 * (r >> 2) + 4 * g;
#pragma unroll
      for (int dt = 0; dt < 4; ++dt) ybuf[qrow * 128 + dt * 32 + c] = y[dt][r];
    }
  }
  __syncthreads();
#pragma unroll
  for (int ww = 1; ww < 4; ++ww) {
    if (w == ww) {
#pragma unroll
      for (int r = 0; r < 16; ++r) {
        const int qrow = (r & 3) + 8 * (r >> 2) + 4 * g;
#pragma unroll
        for (int dt = 0; dt < 4; ++dt) ybuf[qrow * 128 + dt * 32 + c] += y[dt][r];
      }
    }
    __syncthreads();
  }

  // ---- normalize and store: wave w covers q-rows [w*8, w*8+8) --------------
  const int row = w * 8 + (lane >> 3);
  const int d0 = (lane & 7) * 16;
  const float Wt = (wsum[0][row] + wsum[1][row]) + (wsum[2][row] + wsum[3][row]);
  const float winv = 1.0f / Wt;
  float* ob = Og + bhf + (size_t)(q0 + row) * D_ + d0;
#pragma unroll
  for (int i = 0; i < 4; ++i) {
    f32x4 v = *(const f32x4*)&ybuf[row * 128 + d0 + i * 4];
    v[0] *= winv; v[1] *= winv; v[2] *= winv; v[3] *= winv;
    *(f32x4*)(ob + i * 4) = v;
  }
}

// ---- fallback: R3-style kernel (used when ws_size is too small) ------------
__global__ __launch_bounds__(256, 4) void simattn_fb(
    const float* __restrict__ Qg, const float* __restrict__ Kg,
    const float* __restrict__ Vg, float* __restrict__ Og) {
  __shared__ __align__(16) unsigned short kfb[64][DK];
  __shared__ __align__(16) unsigned short vtb[DK][64];
  __shared__ __align__(16) unsigned int   wlb[4][16][32];

  const int tid  = threadIdx.x;
  const int wid  = tid >> 6;
  const int lane = tid & 63;
  const int lr   = lane & 15;
  const int lg   = lane >> 4;

  const int blk  = blockIdx.x;
  const int qblk = blk & 31;
  const int h    = (blk >> 5) & (NH - 1);
  const int b    = blk >> 8;
  const int q0   = qblk * 64;
  const size_t bh = (size_t)b * (T_ * D_) + (size_t)h * DK;

  h16x8 qf[4];
  {
    const float* qp = Qg + bh + (size_t)(q0 + wid * 16 + lr) * D_;
#pragma unroll
    for (int s = 0; s < 4; ++s) {
      const int d0 = s * 32 + lg * 8;
      f32x4 x0 = *(const f32x4*)(qp + d0);
      f32x4 x1 = *(const f32x4*)(qp + d0 + 4);
#pragma unroll
      for (int i = 0; i < 4; ++i) { qf[s][i] = (_Float16)x0[i]; qf[s][i+4] = (_Float16)x1[i]; }
    }
  }
  auto stageK = [&](int kc) {
    const float* kp = Kg + bh + (size_t)kc * 64 * D_;
#pragma unroll
    for (int p = 0; p < 8; ++p) {
      const int j = tid + p * 256;
      const int row = j >> 5, c4 = j & 31;
      f32x4 v = *(const f32x4*)(kp + (size_t)row * D_ + c4 * 4);
      h16x4 hv;
#pragma unroll
      for (int i = 0; i < 4; ++i) hv[i] = (_Float16)v[i];
      const int e = (c4 * 4) ^ ((row & 7) << 3);
      *(s16x4*)&kfb[row][e] = __builtin_bit_cast(s16x4, hv);
    }
  };
  auto qkT = [&](f32x4* st) {
#pragma unroll
    for (int nt = 0; nt < 4; ++nt) st[nt] = (f32x4){0.f, 0.f, 0.f, 0.f};
#pragma unroll
    for (int s = 0; s < 4; ++s) {
#pragma unroll
      for (int nt = 0; nt < 4; ++nt) {
        const int kr = nt * 16 + lr;
        const int e = (s * 32 + lg * 8) ^ ((kr & 7) << 3);
        st[nt] = __builtin_amdgcn_mfma_f32_16x16x32_f16(H8(&kfb[kr][e]), qf[s], st[nt], 0, 0, 0);
      }
    }
  };
  float msc = -3.0e38f, l8 = 0.f;
  for (int kc = 0; kc < 32; ++kc) {
    __syncthreads();
    stageK(kc);
    __syncthreads();
    f32x4 st[4];
    qkT(st);
#pragma unroll
    for (int nt = 0; nt < 4; ++nt)
#pragma unroll
      for (int r = 0; r < 4; ++r) {
        const float s = st[nt][r];
        msc = fmaxf(msc, s);
        l8 += __builtin_amdgcn_exp2f(fmaf(s, SC2, -MOFF2));
      }
  }
  msc = fmaxf(msc, __shfl_xor(msc, 16));
  msc = fmaxf(msc, __shfl_xor(msc, 32));
  l8 += __shfl_xor(l8, 16);
  l8 += __shfl_xor(l8, 32);
  const float pm   = __builtin_amdgcn_exp2f(fmaf(msc, SC2, -MOFF2));
  const float ul2  = (1000.0f / l8) * L2E;
  const float mcu2 = -ul2 * pm;

  f32x4 y[8];
#pragma unroll
  for (int dt = 0; dt < 8; ++dt) y[dt] = (f32x4){0.f, 0.f, 0.f, 0.f};
  float Wl = 0.f;
  const int dv  = tid & 127;
  const int kg0 = tid >> 7;
  for (int kc = 0; kc < 32; ++kc) {
    __syncthreads();
    stageK(kc);
    {
      const float* vp = Vg + bh + (size_t)kc * 64 * D_ + dv;
#pragma unroll
      for (int i = 0; i < 4; ++i) {
        const int kg = kg0 + 2 * i;
        const float* vq = vp + (size_t)kg * 8 * D_;
        u32x4 pv;
        pv[0] = pk2(vq[0], vq[D_]);
        pv[1] = pk2(vq[2 * D_], vq[3 * D_]);
        pv[2] = pk2(vq[4 * D_], vq[5 * D_]);
        pv[3] = pk2(vq[6 * D_], vq[7 * D_]);
        *(u32x4*)&vtb[dv][(kg ^ (dv & 7)) * 8] = pv;
      }
    }
    __syncthreads();
    f32x4 st[4];
    qkT(st);
#pragma unroll
    for (int nt = 0; nt < 4; ++nt) {
      float w[4];
#pragma unroll
      for (int r = 0; r < 4; ++r) {
        const float pp = __builtin_amdgcn_exp2f(fmaf(st[nt][r], SC2, -MOFF2));
        w[r] = __builtin_amdgcn_exp2f(fmaf(pp, ul2, mcu2));
      }
      Wl += (w[0] + w[1]) + (w[2] + w[3]);
      u32x2 pk;
      pk[0] = pk2(w[0], w[1]);
      pk[1] = pk2(w[2], w[3]);
      *(u32x2*)&wlb[wid][lr][(nt * 8 + lg * 2) ^ ((lr & 7) << 2)] = pk;
    }
#pragma unroll
    for (int ks = 0; ks < 2; ++ks) {
      h16x8 af = H8((const unsigned short*)&wlb[wid][lr][(ks * 16 + lg * 4) ^ ((lr & 7) << 2)]);
#pragma unroll
      for (int dt = 0; dt < 8; ++dt) {
        const int d = dt * 16 + lr;
        h16x8 vf = H8(&vtb[d][((ks * 4 + lg) ^ (d & 7)) * 8]);
        y[dt] = __builtin_amdgcn_mfma_f32_16x16x32_f16(af, vf, y[dt], 0, 0, 0);
      }
    }
  }
  Wl += __shfl_xor(Wl, 16);
  Wl += __shfl_xor(Wl, 32);
  const float winv = 1.0f / Wl;
  float* op = Og + bh + (size_t)(q0 + wid * 16) * D_;
#pragma unroll
  for (int r = 0; r < 4; ++r) {
    const float wv = __shfl(winv, lg * 4 + r);
#pragma unroll
    for (int dt = 0; dt < 8; ++dt)
      op[(size_t)(lg * 4 + r) * D_ + dt * 16 + lr] = y[dt][r] * wv;
  }
}

extern "C" void kernel_launch(void* const* d_in, const int* in_sizes, int n_in,
                              void* d_out, int out_size, void* d_ws, size_t ws_size,
                              hipStream_t stream) {
  (void)in_sizes; (void)n_in; (void)out_size;
  const float* Q = (const float*)d_in[0];
  const float* K = (const float*)d_in[1];
  const float* V = (const float*)d_in[2];
  float* O = (float*)d_out;
  const size_t half = (size_t)NB * NH * T_ * DK * 2;  // 16.78 MB per tensor
  if (ws_size >= 2 * half) {
    unsigned short* Kf = (unsigned short*)d_ws;
    unsigned short* Vf = (unsigned short*)((char*)d_ws + half);
    prep9<<<dim3(2048), 256, 0, stream>>>(K, V, Kf, Vf);
    simattn_v11<<<dim3(NWG9), 256, 0, stream>>>(Q, Kf, Vf, O);
  } else {
    simattn_fb<<<dim3(NB * NH * (T_ / 64)), 256, 0, stream>>>(Q, K, V, O);
  }
}